// Round 10
// baseline (145.229 us; speedup 1.0000x reference)
//
#include <hip/hip_runtime.h>

#define FDIM 128
#define EMB 32

typedef __attribute__((ext_vector_type(4))) float f32x4;

static __device__ __forceinline__ void store_nt(float* p, float4 v) {
    f32x4 w; w.x = v.x; w.y = v.y; w.z = v.z; w.w = v.w;
    __builtin_nontemporal_store(w, (f32x4*)p);
}

// ---------------- K1: xe = x @ W  (f32 in, f32 out) ----------------
__global__ __launch_bounds__(256) void k_gemm(const float* __restrict__ x,
                                              const float* __restrict__ Wm,
                                              float* __restrict__ xe) {
    __shared__ float sW[FDIM * EMB];
    const int t = threadIdx.x;
#pragma unroll
    for (int i = 0; i < (FDIM * EMB) / (256 * 4); ++i) {
        int idx = (t + i * 256) * 4;
        *(float4*)(sW + idx) = *(const float4*)(Wm + idx);
    }
    __syncthreads();

    const int r0 = blockIdx.x * 128 + (t >> 3) * 4;
    const int e0 = (t & 7) * 4;

    float acc[4][4];
#pragma unroll
    for (int i = 0; i < 4; ++i)
#pragma unroll
        for (int j = 0; j < 4; ++j) acc[i][j] = 0.f;

    for (int k = 0; k < FDIM; k += 4) {
        float4 w0 = *(const float4*)(sW + (k + 0) * EMB + e0);
        float4 w1 = *(const float4*)(sW + (k + 1) * EMB + e0);
        float4 w2 = *(const float4*)(sW + (k + 2) * EMB + e0);
        float4 w3 = *(const float4*)(sW + (k + 3) * EMB + e0);
#pragma unroll
        for (int rr = 0; rr < 4; ++rr) {
            float4 xq = *(const float4*)(x + (size_t)(r0 + rr) * FDIM + k);
            acc[rr][0] += xq.x * w0.x + xq.y * w1.x + xq.z * w2.x + xq.w * w3.x;
            acc[rr][1] += xq.x * w0.y + xq.y * w1.y + xq.z * w2.y + xq.w * w3.y;
            acc[rr][2] += xq.x * w0.z + xq.y * w1.z + xq.z * w2.z + xq.w * w3.z;
            acc[rr][3] += xq.x * w0.w + xq.y * w1.w + xq.z * w2.w + xq.w * w3.w;
        }
    }

#pragma unroll
    for (int rr = 0; rr < 4; ++rr) {
        const size_t r = (size_t)(r0 + rr);
        float4 o; o.x = acc[rr][0]; o.y = acc[rr][1]; o.z = acc[rr][2]; o.w = acc[rr][3];
        *(float4*)(xe + r * EMB + e0) = o;
    }
}

// ---------------- K2a: per-block partial sum/min/max over graph-0 rows ----------------
__global__ __launch_bounds__(256) void k_stats_a(const float* __restrict__ xe,
                                                 float* __restrict__ psum,
                                                 float* __restrict__ pmin,
                                                 float* __restrict__ pmax) {
    __shared__ float rs[256], rmn[256], rmx[256];
    const int t = threadIdx.x;
    const int d = t & 31, rg = t >> 5;
    const int r0 = blockIdx.x * 32;

    float s = 0.f, mn = 3.4e38f, mx = -3.4e38f;
#pragma unroll
    for (int it = 0; it < 4; ++it) {
        float v = xe[(size_t)(r0 + rg + it * 8) * EMB + d];
        s += v; mn = fminf(mn, v); mx = fmaxf(mx, v);
    }
    rs[t] = s; rmn[t] = mn; rmx[t] = mx;
    __syncthreads();
#pragma unroll
    for (int st = 128; st >= 32; st >>= 1) {
        if (t < st) {
            rs[t] += rs[t + st];
            rmn[t] = fminf(rmn[t], rmn[t + st]);
            rmx[t] = fmaxf(rmx[t], rmx[t + st]);
        }
        __syncthreads();
    }
    if (t < 32) {
        psum[blockIdx.x * 32 + t] = rs[t];
        pmin[blockIdx.x * 32 + t] = rmn[t];
        pmax[blockIdx.x * 32 + t] = rmx[t];
    }
}

// ---------------- K2b: finalize centroid + scale ----------------
__global__ __launch_bounds__(64) void k_stats_b(const float* __restrict__ psum,
                                                const float* __restrict__ pmin,
                                                const float* __restrict__ pmax,
                                                int nb, int n,
                                                float* __restrict__ stats) {
    const int t = threadIdx.x;
    const int d = t & 31;
    float s = 0.f, mn = 3.4e38f, mx = -3.4e38f;
    for (int b = 0; b < nb; ++b) {
        s += psum[b * 32 + d];
        mn = fminf(mn, pmin[b * 32 + d]);
        mx = fmaxf(mx, pmax[b * 32 + d]);
    }
    const float c = s / (float)n;
    float dev = fmaxf(mx - c, c - mn);
#pragma unroll
    for (int off = 16; off >= 1; off >>= 1)
        dev = fmaxf(dev, __shfl_xor(dev, off, 32));
    if (t < 32) stats[t] = c;
    if (t == 0) stats[EMB] = 0.9f / dev;
}

// ---------------- K3: fused pairwise D -> sigmoid + edge_index fill ----------------
// 128x128 tile, 256 threads, 8x8 micro-tile (halves LDS-read inst/output vs 4x4).
// Cols owned as {tx*4, 64+tx*4}: every nt-store instruction is 4x256B dense.
// Swizzle key ((row>>2)&7 ^ (row>>5)&1)<<2: A-reads and B-reads conflict-free.
// sq folded into staging via 8-lane shfl reduce (single barrier).
#define KEY(r) (((((r) >> 2) & 7) ^ (((r) >> 5) & 1)) << 2)
__global__ __launch_bounds__(256) void k_edges(const float* __restrict__ xe,
                                               const float* __restrict__ stats,
                                               const float* __restrict__ tptr,
                                               const float* __restrict__ thptr,
                                               float* __restrict__ wts,
                                               float* __restrict__ srcp,
                                               float* __restrict__ dstp,
                                               int n) {
    __shared__ float shA[128 * 32];
    __shared__ float shB[128 * 32];
    __shared__ float sqA[128], sqB[128];

    const int g = blockIdx.z;
    const int i0 = blockIdx.y * 128, j0 = blockIdx.x * 128;
    const int t = threadIdx.x;
    const float scale = stats[EMB];

    // ---- stage 256 rows (128 A + 128 B), compute row sumsq inline ----
#pragma unroll
    for (int c = 0; c < 8; ++c) {
        int id = t + c * 256;
        int side = id >> 10;                 // 0=A, 1=B
        int row = (id >> 3) & 127;
        int dc = (id & 7) * 4;
        int dswz = dc ^ KEY(row);
        int grow = (side ? j0 : i0) + row;
        float4 cen = *(const float4*)(stats + dc);
        float4 v = *(const float4*)(xe + ((size_t)g * n + grow) * EMB + dc);
        v.x = (v.x - cen.x) * scale; v.y = (v.y - cen.y) * scale;
        v.z = (v.z - cen.z) * scale; v.w = (v.w - cen.w) * scale;
        float* sh = side ? shB : shA;
        *(float4*)(sh + row * 32 + dswz) = v;
        float ps = v.x * v.x + v.y * v.y + v.z * v.z + v.w * v.w;
        ps += __shfl_xor(ps, 1);
        ps += __shfl_xor(ps, 2);
        ps += __shfl_xor(ps, 4);
        if ((t & 7) == 0) { if (side) sqB[row] = ps; else sqA[row] = ps; }
    }
    __syncthreads();

    // ---- compute: thread (ty=t>>4, tx=t&15): rows ty*8+u, cols {tx*4+v, 64+tx*4+v} ----
    const int ty = t >> 4, tx = t & 15;
    int rowA[8], ka[8];
#pragma unroll
    for (int u = 0; u < 8; ++u) {
        int r = ty * 8 + u;
        rowA[u] = r * 32;
        ka[u] = KEY(r);
    }
    int rowB[4], kb[4];
#pragma unroll
    for (int v = 0; v < 4; ++v) {
        int r = tx * 4 + v;
        rowB[v] = r * 32;
        kb[v] = KEY(r);                      // KEY(64+r) == KEY(r)
    }

    float acc[8][8];
#pragma unroll
    for (int i = 0; i < 8; ++i)
#pragma unroll
        for (int j = 0; j < 8; ++j) acc[i][j] = 0.f;

#pragma unroll
    for (int d = 0; d < EMB; d += 4) {
        float4 a[8];
#pragma unroll
        for (int u = 0; u < 8; ++u)
            a[u] = *(const float4*)(shA + rowA[u] + (d ^ ka[u]));
#pragma unroll
        for (int v = 0; v < 4; ++v) {
            const int ds = d ^ kb[v];
            float4 b = *(const float4*)(shB + rowB[v] + ds);
#pragma unroll
            for (int u = 0; u < 8; ++u)
                acc[u][v] += a[u].x * b.x + a[u].y * b.y + a[u].z * b.z + a[u].w * b.w;
            float4 b2 = *(const float4*)(shB + rowB[v] + 64 * 32 + ds);
#pragma unroll
            for (int u = 0; u < 8; ++u)
                acc[u][v + 4] += a[u].x * b2.x + a[u].y * b2.y + a[u].z * b2.z + a[u].w * b2.w;
        }
    }

    const float T = *tptr;
    const float TH = fabsf(*thptr);
    const int gn = g * n;
    const size_t gbase = (size_t)g * n * n;

    const float4 sq1 = *(const float4*)(sqB + tx * 4);
    const float4 sq2 = *(const float4*)(sqB + 64 + tx * 4);
    const float db1 = (float)(gn + j0 + tx * 4);
    const float db2 = db1 + 64.f;
    float4 dstA; dstA.x = db1; dstA.y = db1 + 1.f; dstA.z = db1 + 2.f; dstA.w = db1 + 3.f;
    float4 dstB; dstB.x = db2; dstB.y = db2 + 1.f; dstB.z = db2 + 2.f; dstB.w = db2 + 3.f;

#pragma unroll
    for (int u = 0; u < 8; ++u) {
        const int row = i0 + ty * 8 + u;
        const float sa = sqA[ty * 8 + u];
        const size_t off = gbase + (size_t)row * n + j0 + tx * 4;

        float4 w1, w2;
        {
            float D0 = fmaxf(sa + sq1.x - 2.f * acc[u][0], 0.f);
            float D1 = fmaxf(sa + sq1.y - 2.f * acc[u][1], 0.f);
            float D2 = fmaxf(sa + sq1.z - 2.f * acc[u][2], 0.f);
            float D3 = fmaxf(sa + sq1.w - 2.f * acc[u][3], 0.f);
            w1.x = __builtin_amdgcn_rcpf(1.f + __expf(-(T * (TH - D0))));
            w1.y = __builtin_amdgcn_rcpf(1.f + __expf(-(T * (TH - D1))));
            w1.z = __builtin_amdgcn_rcpf(1.f + __expf(-(T * (TH - D2))));
            w1.w = __builtin_amdgcn_rcpf(1.f + __expf(-(T * (TH - D3))));
            float E0 = fmaxf(sa + sq2.x - 2.f * acc[u][4], 0.f);
            float E1 = fmaxf(sa + sq2.y - 2.f * acc[u][5], 0.f);
            float E2 = fmaxf(sa + sq2.z - 2.f * acc[u][6], 0.f);
            float E3 = fmaxf(sa + sq2.w - 2.f * acc[u][7], 0.f);
            w2.x = __builtin_amdgcn_rcpf(1.f + __expf(-(T * (TH - E0))));
            w2.y = __builtin_amdgcn_rcpf(1.f + __expf(-(T * (TH - E1))));
            w2.z = __builtin_amdgcn_rcpf(1.f + __expf(-(T * (TH - E2))));
            w2.w = __builtin_amdgcn_rcpf(1.f + __expf(-(T * (TH - E3))));
        }
        store_nt(wts + off, w1);
        store_nt(wts + off + 64, w2);

        const float sv = (float)(gn + row);
        float4 s4; s4.x = sv; s4.y = sv; s4.z = sv; s4.w = sv;
        store_nt(srcp + off, s4);
        store_nt(srcp + off + 64, s4);
        store_nt(dstp + off, dstA);
        store_nt(dstp + off + 64, dstB);
    }
}

extern "C" void kernel_launch(void* const* d_in, const int* in_sizes, int n_in,
                              void* d_out, int out_size, void* d_ws, size_t ws_size,
                              hipStream_t stream) {
    const float* x     = (const float*)d_in[0];
    const float* Wm    = (const float*)d_in[1];
    const float* tptr  = (const float*)d_in[2];
    const float* thptr = (const float*)d_in[3];

    const int N = in_sizes[0] / FDIM;                       // 32768
    const long long rem = (long long)out_size - (long long)N * EMB;
    int G = (rem > 0) ? (int)((3LL * N * N) / rem) : 32;    // 32
    if (G <= 0) G = 32;
    const int n = N / G;                                    // 1024
    const int nb = n / 32;

    float* out  = (float*)d_out;
    float* xe   = out;
    const long long M = (long long)G * n * n;
    float* srcp = out + (size_t)N * EMB;
    float* dstp = srcp + (size_t)M;
    float* wts  = dstp + (size_t)M;

    float* stats = (float*)d_ws;
    float* psum  = stats + 64;
    float* pmin  = psum + (size_t)nb * 32;
    float* pmax  = pmin + (size_t)nb * 32;

    k_gemm<<<N / 128, 256, 0, stream>>>(x, Wm, xe);
    k_stats_a<<<nb, 256, 0, stream>>>(xe, psum, pmin, pmax);
    k_stats_b<<<1, 64, 0, stream>>>(psum, pmin, pmax, nb, n, stats);
    dim3 ge(n / 128, n / 128, G);
    k_edges<<<ge, 256, 0, stream>>>(xe, stats, tptr, thptr, wts, srcp, dstp, n);
}

// Round 12
// 108.316 us; speedup vs baseline: 1.3408x; 1.3408x over previous
//
#include <hip/hip_runtime.h>

#define FDIM 128
#define EMB 32

typedef __attribute__((ext_vector_type(4))) float f32x4;
typedef __fp16 h2 __attribute__((ext_vector_type(2)));

static __device__ __forceinline__ void store_nt(float* p, float4 v) {
    f32x4 w; w.x = v.x; w.y = v.y; w.z = v.z; w.w = v.w;
    __builtin_nontemporal_store(w, (f32x4*)p);
}

static __device__ __forceinline__ unsigned pkh2(float x, float y) {
    h2 h = __builtin_amdgcn_cvt_pkrtz(x, y);
    union { h2 h; unsigned u; } c; c.h = h; return c.u;
}

static __device__ __forceinline__ float fdot2u(unsigned a, unsigned b, float c) {
    union { unsigned u; h2 h; } ua, ub; ua.u = a; ub.u = b;
#if __has_builtin(__builtin_amdgcn_fdot2)
    return __builtin_amdgcn_fdot2(ua.h, ub.h, c, false);
#else
    return c + (float)ua.h.x * (float)ub.h.x + (float)ua.h.y * (float)ub.h.y;
#endif
}

// ---------------- K1: xe = x @ W  (f32 in, f32 out) ----------------
__global__ __launch_bounds__(256) void k_gemm(const float* __restrict__ x,
                                              const float* __restrict__ Wm,
                                              float* __restrict__ xe) {
    __shared__ float sW[FDIM * EMB];
    const int t = threadIdx.x;
#pragma unroll
    for (int i = 0; i < (FDIM * EMB) / (256 * 4); ++i) {
        int idx = (t + i * 256) * 4;
        *(float4*)(sW + idx) = *(const float4*)(Wm + idx);
    }
    __syncthreads();

    const int r0 = blockIdx.x * 128 + (t >> 3) * 4;
    const int e0 = (t & 7) * 4;

    float acc[4][4];
#pragma unroll
    for (int i = 0; i < 4; ++i)
#pragma unroll
        for (int j = 0; j < 4; ++j) acc[i][j] = 0.f;

    for (int k = 0; k < FDIM; k += 4) {
        float4 w0 = *(const float4*)(sW + (k + 0) * EMB + e0);
        float4 w1 = *(const float4*)(sW + (k + 1) * EMB + e0);
        float4 w2 = *(const float4*)(sW + (k + 2) * EMB + e0);
        float4 w3 = *(const float4*)(sW + (k + 3) * EMB + e0);
#pragma unroll
        for (int rr = 0; rr < 4; ++rr) {
            float4 xq = *(const float4*)(x + (size_t)(r0 + rr) * FDIM + k);
            acc[rr][0] += xq.x * w0.x + xq.y * w1.x + xq.z * w2.x + xq.w * w3.x;
            acc[rr][1] += xq.x * w0.y + xq.y * w1.y + xq.z * w2.y + xq.w * w3.y;
            acc[rr][2] += xq.x * w0.z + xq.y * w1.z + xq.z * w2.z + xq.w * w3.z;
            acc[rr][3] += xq.x * w0.w + xq.y * w1.w + xq.z * w2.w + xq.w * w3.w;
        }
    }

#pragma unroll
    for (int rr = 0; rr < 4; ++rr) {
        const size_t r = (size_t)(r0 + rr);
        float4 o; o.x = acc[rr][0]; o.y = acc[rr][1]; o.z = acc[rr][2]; o.w = acc[rr][3];
        *(float4*)(xe + r * EMB + e0) = o;
    }
}

// ---------------- K2a: per-block partial sum/min/max over graph-0 rows ----------------
__global__ __launch_bounds__(256) void k_stats_a(const float* __restrict__ xe,
                                                 float* __restrict__ psum,
                                                 float* __restrict__ pmin,
                                                 float* __restrict__ pmax) {
    __shared__ float rs[256], rmn[256], rmx[256];
    const int t = threadIdx.x;
    const int d = t & 31, rg = t >> 5;
    const int r0 = blockIdx.x * 32;

    float s = 0.f, mn = 3.4e38f, mx = -3.4e38f;
#pragma unroll
    for (int it = 0; it < 4; ++it) {
        float v = xe[(size_t)(r0 + rg + it * 8) * EMB + d];
        s += v; mn = fminf(mn, v); mx = fmaxf(mx, v);
    }
    rs[t] = s; rmn[t] = mn; rmx[t] = mx;
    __syncthreads();
#pragma unroll
    for (int st = 128; st >= 32; st >>= 1) {
        if (t < st) {
            rs[t] += rs[t + st];
            rmn[t] = fminf(rmn[t], rmn[t + st]);
            rmx[t] = fmaxf(rmx[t], rmx[t + st]);
        }
        __syncthreads();
    }
    if (t < 32) {
        psum[blockIdx.x * 32 + t] = rs[t];
        pmin[blockIdx.x * 32 + t] = rmn[t];
        pmax[blockIdx.x * 32 + t] = rmx[t];
    }
}

// ---------------- K2b: finalize centroid + scale ----------------
__global__ __launch_bounds__(64) void k_stats_b(const float* __restrict__ psum,
                                                const float* __restrict__ pmin,
                                                const float* __restrict__ pmax,
                                                int nb, int n,
                                                float* __restrict__ stats) {
    const int t = threadIdx.x;
    const int d = t & 31;
    float s = 0.f, mn = 3.4e38f, mx = -3.4e38f;
    for (int b = 0; b < nb; ++b) {
        s += psum[b * 32 + d];
        mn = fminf(mn, pmin[b * 32 + d]);
        mx = fmaxf(mx, pmax[b * 32 + d]);
    }
    const float c = s / (float)n;
    float dev = fmaxf(mx - c, c - mn);
#pragma unroll
    for (int off = 16; off >= 1; off >>= 1)
        dev = fmaxf(dev, __shfl_xor(dev, off, 32));
    if (t < 32) stats[t] = c;
    if (t == 0) stats[EMB] = 0.9f / dev;
}

// ---------------- K3: fused pairwise D -> sigmoid + edge_index fill ----------------
// Round-8 geometry: grid (n/64, n/64, G); 256 thr; 64x64 tile; 4x4 micro-tile;
// dense float4 nt-stores. NEW: f16 dot engine. LDS holds half2 tiles in
// [dim-pair][row] layout, stride 68 words (16B-aligned rows of 64 half2 + pad:
// all reads/writes <=2-way bank aliasing, no swizzle). Each compute read is
// ds_read_b128 = 4 rows x 1 dim-pair; 32 reads/thread (was 64 b128 of f32).
// Dot products via v_dot2_f32_f16 (f32 accumulate), 256 insts (was 512 FMA).
#define DPS 68  // words per dim-pair row (64 + 4 pad)
__global__ __launch_bounds__(256) void k_edges(const float* __restrict__ xe,
                                               const float* __restrict__ stats,
                                               const float* __restrict__ tptr,
                                               const float* __restrict__ thptr,
                                               float* __restrict__ wts,
                                               float* __restrict__ srcp,
                                               float* __restrict__ dstp,
                                               int n) {
    __shared__ unsigned shA[16 * DPS];
    __shared__ unsigned shB[16 * DPS];
    __shared__ __attribute__((aligned(16))) float sqA[64];
    __shared__ __attribute__((aligned(16))) float sqB[64];

    const int g = blockIdx.z;
    const int i0 = blockIdx.y * 64, j0 = blockIdx.x * 64;
    const int t = threadIdx.x;
    const float scale = stats[EMB];

    const float* baseA = xe + ((size_t)g * n + i0) * EMB;
    const float* baseB = xe + ((size_t)g * n + j0) * EMB;

    // stage + normalize + f16-pack + inline row-sumsq (8 lanes per row)
#pragma unroll
    for (int c = 0; c < 2; ++c) {
        int id = t + c * 256;
        int row = id >> 3;          // 0..63
        int dc = (id & 7) * 4;      // dim 0,4,..28
        int dp = dc >> 1;           // dim-pair 0,2,..14
        float4 cen = *(const float4*)(stats + dc);
        float4 va = *(const float4*)(baseA + (size_t)row * EMB + dc);
        float4 vb = *(const float4*)(baseB + (size_t)row * EMB + dc);
        va.x = (va.x - cen.x) * scale; va.y = (va.y - cen.y) * scale;
        va.z = (va.z - cen.z) * scale; va.w = (va.w - cen.w) * scale;
        vb.x = (vb.x - cen.x) * scale; vb.y = (vb.y - cen.y) * scale;
        vb.z = (vb.z - cen.z) * scale; vb.w = (vb.w - cen.w) * scale;
        shA[dp * DPS + row]       = pkh2(va.x, va.y);
        shA[(dp + 1) * DPS + row] = pkh2(va.z, va.w);
        shB[dp * DPS + row]       = pkh2(vb.x, vb.y);
        shB[(dp + 1) * DPS + row] = pkh2(vb.z, vb.w);
        float pa = va.x * va.x + va.y * va.y + va.z * va.z + va.w * va.w;
        float pb = vb.x * vb.x + vb.y * vb.y + vb.z * vb.z + vb.w * vb.w;
        pa += __shfl_xor(pa, 1); pb += __shfl_xor(pb, 1);
        pa += __shfl_xor(pa, 2); pb += __shfl_xor(pb, 2);
        pa += __shfl_xor(pa, 4); pb += __shfl_xor(pb, 4);
        if ((t & 7) == 0) { sqA[row] = pa; sqB[row] = pb; }
    }
    __syncthreads();

    const int ti = t >> 4, tj = t & 15;
    float acc[4][4];
#pragma unroll
    for (int i = 0; i < 4; ++i)
#pragma unroll
        for (int j = 0; j < 4; ++j) acc[i][j] = 0.f;

#pragma unroll
    for (int dp = 0; dp < 16; ++dp) {
        uint4 ua = *(const uint4*)(shA + dp * DPS + ti * 4);  // rows ti*4..+3
        uint4 ub = *(const uint4*)(shB + dp * DPS + tj * 4);  // rows tj*4..+3
        unsigned av[4] = { ua.x, ua.y, ua.z, ua.w };
        unsigned bv[4] = { ub.x, ub.y, ub.z, ub.w };
#pragma unroll
        for (int u = 0; u < 4; ++u)
#pragma unroll
            for (int v = 0; v < 4; ++v)
                acc[u][v] = fdot2u(av[u], bv[v], acc[u][v]);
    }

    const float T = *tptr;
    const float TH = fabsf(*thptr);
    const int gn = g * n;
    const size_t gbase = (size_t)g * n * n;

    const float4 sq4 = *(const float4*)(sqB + tj * 4);
    const float dbase = (float)(gn + j0 + tj * 4);
    float4 dst4; dst4.x = dbase; dst4.y = dbase + 1.f; dst4.z = dbase + 2.f; dst4.w = dbase + 3.f;

#pragma unroll
    for (int u = 0; u < 4; ++u) {
        const int row = i0 + ti * 4 + u;
        const float sa = sqA[ti * 4 + u];
        const size_t off = gbase + (size_t)row * n + j0 + tj * 4;

        float4 w;
        {
            float D0 = fmaxf(sa + sq4.x - 2.f * acc[u][0], 0.f);
            float D1 = fmaxf(sa + sq4.y - 2.f * acc[u][1], 0.f);
            float D2 = fmaxf(sa + sq4.z - 2.f * acc[u][2], 0.f);
            float D3 = fmaxf(sa + sq4.w - 2.f * acc[u][3], 0.f);
            w.x = __builtin_amdgcn_rcpf(1.f + __expf(-(T * (TH - D0))));
            w.y = __builtin_amdgcn_rcpf(1.f + __expf(-(T * (TH - D1))));
            w.z = __builtin_amdgcn_rcpf(1.f + __expf(-(T * (TH - D2))));
            w.w = __builtin_amdgcn_rcpf(1.f + __expf(-(T * (TH - D3))));
        }
        store_nt(wts + off, w);

        const float sv = (float)(gn + row);
        float4 s4; s4.x = sv; s4.y = sv; s4.z = sv; s4.w = sv;
        store_nt(srcp + off, s4);
        store_nt(dstp + off, dst4);
    }
}

extern "C" void kernel_launch(void* const* d_in, const int* in_sizes, int n_in,
                              void* d_out, int out_size, void* d_ws, size_t ws_size,
                              hipStream_t stream) {
    const float* x     = (const float*)d_in[0];
    const float* Wm    = (const float*)d_in[1];
    const float* tptr  = (const float*)d_in[2];
    const float* thptr = (const float*)d_in[3];

    const int N = in_sizes[0] / FDIM;                       // 32768
    const long long rem = (long long)out_size - (long long)N * EMB;
    int G = (rem > 0) ? (int)((3LL * N * N) / rem) : 32;    // 32
    if (G <= 0) G = 32;
    const int n = N / G;                                    // 1024
    const int nb = n / 32;

    float* out  = (float*)d_out;
    float* xe   = out;
    const long long M = (long long)G * n * n;
    float* srcp = out + (size_t)N * EMB;
    float* dstp = srcp + (size_t)M;
    float* wts  = dstp + (size_t)M;

    float* stats = (float*)d_ws;
    float* psum  = stats + 64;
    float* pmin  = psum + (size_t)nb * 32;
    float* pmax  = pmin + (size_t)nb * 32;

    k_gemm<<<N / 128, 256, 0, stream>>>(x, Wm, xe);
    k_stats_a<<<nb, 256, 0, stream>>>(xe, psum, pmin, pmax);
    k_stats_b<<<1, 64, 0, stream>>>(psum, pmin, pmax, nb, n, stats);
    dim3 ge(n / 64, n / 64, G);
    k_edges<<<ge, 256, 0, stream>>>(xe, stats, tptr, thptr, wts, srcp, dstp, n);
}